// Round 8
// baseline (1009.203 us; speedup 1.0000x reference)
//
#include <hip/hip_runtime.h>

typedef unsigned short ushort_t;
typedef unsigned int uint32;
typedef __attribute__((ext_vector_type(8))) short short8;
typedef __attribute__((ext_vector_type(4))) float floatx4;

static __device__ __forceinline__ ushort_t f2bf(float f) {
    union { float f; unsigned int u; } c; c.f = f;
    unsigned int u = c.u;
    return (ushort_t)((u + 0x7FFFu + ((u >> 16) & 1u)) >> 16);
}

// ---------------- weight f32 -> bf16 conversion ----------------
__global__ __launch_bounds__(256) void cvt_weights(
    const float* __restrict__ w0, const float* __restrict__ w1,
    const float* __restrict__ w2, const float* __restrict__ w3,
    ushort_t* __restrict__ o0, ushort_t* __restrict__ o1,
    ushort_t* __restrict__ o2, ushort_t* __restrict__ o3)
{
    int i = blockIdx.x * 256 + threadIdx.x;
    if (i < 442368) o0[i] = f2bf(w0[i]);   // qkv_w [1152,384]
    if (i < 147456) o1[i] = f2bf(w1[i]);   // proj_w [384,384]
    if (i < 589824) o2[i] = f2bf(w2[i]);   // mlp_w1 [1536,384]
    if (i < 589824) o3[i] = f2bf(w3[i]);   // mlp_w2 [384,1536]
}

// ---------------- rel-pos bias, TRANSPOSED: biasT[h][j(key)][q(query)] f32 ----
__global__ __launch_bounds__(256) void build_bias(
    const float* __restrict__ rpb, float* __restrict__ biasT)
{
    int idx = blockIdx.x * 256 + threadIdx.x;   // < 12*64*64 = 49152
    int h = idx >> 12, j = (idx >> 6) & 63, q = idx & 63;
    float v = 0.f;
    if (q < 49 && j < 49) {
        int pi = q / 7, pj = q - pi * 7;        // query coords
        int qi = j / 7, qj = j - qi * 7;        // key coords
        v = rpb[((pi - qi + 6) * 13 + (pj - qj + 6)) * 12 + h];
    }
    biasT[idx] = v;   // [h][j][q]
}

// ---------------- LayerNorm (one wave per token); WPART fuses roll+window partition
template<bool WPART>
__global__ __launch_bounds__(256) void ln_kernel(
    const float* __restrict__ x, const float* __restrict__ g,
    const float* __restrict__ b, ushort_t* __restrict__ out)
{
    int wave = threadIdx.x >> 6, lane = threadIdx.x & 63;
    int tkn = blockIdx.x * 4 + wave;       // output row M (0..50175)
    const float* src;
    if (WPART) {
        int w = tkn / 49, n = tkn - w * 49;
        int bb = w >> 6, wrem = w & 63;
        int wi = wrem >> 3, wj = wrem & 7;
        int pi = n / 7, pj = n - pi * 7;
        int si = wi * 7 + pi + 3; if (si >= 56) si -= 56;   // roll(-3): gather at +3
        int sj = wj * 7 + pj + 3; if (sj >= 56) sj -= 56;
        src = x + ((size_t)bb * 3136 + si * 56 + sj) * 384;
    } else {
        src = x + (size_t)tkn * 384;
    }
    float v[6];
    float s = 0.f, sq = 0.f;
#pragma unroll
    for (int it = 0; it < 3; ++it) {
        float2 t = *(const float2*)(src + it * 128 + lane * 2);
        v[it * 2] = t.x; v[it * 2 + 1] = t.y;
        s += t.x + t.y; sq += t.x * t.x + t.y * t.y;
    }
#pragma unroll
    for (int off = 32; off; off >>= 1) {
        s += __shfl_xor(s, off, 64);
        sq += __shfl_xor(sq, off, 64);
    }
    float mean = s * (1.f / 384.f);
    float rstd = rsqrtf(sq * (1.f / 384.f) - mean * mean + 1e-5f);
    ushort_t* dst = out + (size_t)tkn * 384;
#pragma unroll
    for (int it = 0; it < 3; ++it) {
        int c = it * 128 + lane * 2;
        float2 gg = *(const float2*)(g + c);
        float2 bb2 = *(const float2*)(b + c);
        float y0 = (v[it * 2] - mean) * rstd * gg.x + bb2.x;
        float y1 = (v[it * 2 + 1] - mean) * rstd * gg.y + bb2.y;
        uint32 pack = ((uint32)f2bf(y0)) | (((uint32)f2bf(y1)) << 16);
        *(uint32*)(dst + c) = pack;
    }
}

// ---------------- bf16 GEMM, REGISTER-FRAGMENT / NO-LDS / NO-BARRIER ----------
// Y = A[M,K] @ Bw[N,K]^T. 128x128 block = 2x2 waves, each 64x64 out (4x4 frags).
// MFMA A/B operands gathered DIRECTLY from global (16B/lane, quad-strided):
// per-K-step working set (A 16KB + B 16KB) fits L1; weights are L2-resident.
// K is a template constant -> loop fully unrolls into loads with immediate
// offsets + MFMA; no loop VALU, no LDS, no __syncthreads -> waves slip freely
// over memory latency (same mechanism that fixed attn in round 7).
// 1-D grid, bijective XCD-chunked swizzle (T1).
// EPI 0: +bias, scale q cols, bf16 out (QKV)
// EPI 1: +bias, exact GELU, bf16 out (MLP1)
// EPI 2: +bias, window-reverse+unshift+residual(x), f32 out (PROJ, N=384)
// EPI 3: +bias, +resid, f32 out (MLP2, N=384)
template<int EPI, int K>
__global__ __launch_bounds__(256, 2) void gemm_rf(
    const ushort_t* __restrict__ A, const ushort_t* __restrict__ Bw,
    const float* __restrict__ bias, void* __restrict__ out,
    const float* __restrict__ resid, int M, int N)
{
    int tid = threadIdx.x;

    // bijective XCD-chunked swizzle (m204)
    int nwg = gridDim.x;
    int orig = blockIdx.x;
    int xcd = orig & 7, lid = orig >> 3;
    int q8 = nwg >> 3, r8 = nwg & 7;
    int swz = (xcd < r8 ? xcd * (q8 + 1) : r8 * (q8 + 1) + (xcd - r8) * q8) + lid;
    int bnT = N >> 7;
    int bm = swz / bnT, bn = swz - bm * bnT;

    int wv = tid >> 6, lane = tid & 63;
    int wr = wv >> 1, wc = wv & 1;               // 2x2 waves, 64x64 out each
    int quad = lane >> 4, l15 = lane & 15;

    floatx4 acc[4][4];
#pragma unroll
    for (int mi = 0; mi < 4; ++mi)
#pragma unroll
        for (int ni = 0; ni < 4; ++ni)
            acc[mi][ni] = (floatx4){0.f, 0.f, 0.f, 0.f};

    // per-lane fragment base pointers (one per fragment row); loads inside the
    // unrolled loop use compile-time byte offsets (kt*128 + kh*64 <= 3072 < 4095)
    const ushort_t* Ab[4];
    const ushort_t* Bb[4];
#pragma unroll
    for (int mi = 0; mi < 4; ++mi)
        Ab[mi] = A + (size_t)(bm * 128 + wr * 64 + mi * 16 + l15) * K + quad * 8;
#pragma unroll
    for (int ni = 0; ni < 4; ++ni)
        Bb[ni] = Bw + (size_t)(bn * 128 + wc * 64 + ni * 16 + l15) * K + quad * 8;

#pragma unroll
    for (int kt = 0; kt < K / 64; ++kt) {
        short8 af[4][2], bf[4][2];
#pragma unroll
        for (int mi = 0; mi < 4; ++mi) {
            af[mi][0] = *(const short8*)(Ab[mi] + kt * 64);
            af[mi][1] = *(const short8*)(Ab[mi] + kt * 64 + 32);
        }
#pragma unroll
        for (int ni = 0; ni < 4; ++ni) {
            bf[ni][0] = *(const short8*)(Bb[ni] + kt * 64);
            bf[ni][1] = *(const short8*)(Bb[ni] + kt * 64 + 32);
        }
#pragma unroll
        for (int kh = 0; kh < 2; ++kh)
#pragma unroll
            for (int mi = 0; mi < 4; ++mi)
#pragma unroll
                for (int ni = 0; ni < 4; ++ni)
                    acc[mi][ni] = __builtin_amdgcn_mfma_f32_16x16x32_bf16(
                        af[mi][kh], bf[ni][kh], acc[mi][ni], 0, 0, 0);
    }

    if (EPI == 2) {
        // window-reverse + unshift + residual; row mapping hoisted per row
        float bv4[4];
#pragma unroll
        for (int ni = 0; ni < 4; ++ni) bv4[ni] = bias[bn * 128 + wc * 64 + ni * 16 + l15];
#pragma unroll
        for (int mi = 0; mi < 4; ++mi) {
#pragma unroll
            for (int r = 0; r < 4; ++r) {
                int gm = bm * 128 + wr * 64 + mi * 16 + quad * 4 + r;
                int wdx = gm / 49, n = gm - wdx * 49;
                int b = wdx >> 6, wrem = wdx & 63;
                int wi = wrem >> 3, wj = wrem & 7;
                int pi = n / 7, pj = n - pi * 7;
                int i = wi * 7 + pi + 3; if (i >= 56) i -= 56;  // roll(+3)
                int j = wj * 7 + pj + 3; if (j >= 56) j -= 56;
                size_t base = ((size_t)b * 3136 + i * 56 + j) * 384;
#pragma unroll
                for (int ni = 0; ni < 4; ++ni) {
                    size_t dst = base + bn * 128 + wc * 64 + ni * 16 + l15;
                    ((float*)out)[dst] = resid[dst] + acc[mi][ni][r] + bv4[ni];
                }
            }
        }
    } else {
#pragma unroll
        for (int mi = 0; mi < 4; ++mi) {
#pragma unroll
            for (int ni = 0; ni < 4; ++ni) {
                int gn = bn * 128 + wc * 64 + ni * 16 + l15;
                float bv = bias[gn];
#pragma unroll
                for (int r = 0; r < 4; ++r) {
                    int gm = bm * 128 + wr * 64 + mi * 16 + quad * 4 + r;
                    float v = acc[mi][ni][r] + bv;
                    if (EPI == 0) {
                        if (gn < 384) v *= 0.17677669529663689f;   // hd^-0.5 on q
                        ((ushort_t*)out)[(size_t)gm * N + gn] = f2bf(v);
                    } else if (EPI == 1) {
                        v = 0.5f * v * (1.f + erff(v * 0.70710678118654752f));
                        ((ushort_t*)out)[(size_t)gm * N + gn] = f2bf(v);
                    } else {
                        size_t dst = (size_t)gm * 384 + gn;
                        ((float*)out)[dst] = resid[dst] + v;
                    }
                }
            }
        }
    }
}

// ---------------- window attention v2 (round 7, kept): no barriers ------------
__global__ __launch_bounds__(256) void attn_kernel(
    const ushort_t* __restrict__ qkv,   // [50176,1152] bf16 (q pre-scaled)
    const float* __restrict__ biasT,    // [12][64 j][64 q] f32
    ushort_t* __restrict__ O)           // [50176,384] bf16
{
    __shared__ __align__(16) ushort_t Pl[4][64 * 64];   // 32 KB
    int wave = threadIdx.x >> 6;
    int lane = threadIdx.x & 63;
    int id = blockIdx.x * 4 + wave;     // 0..12287
    int w = id / 12, h = id % 12;
    int quad = lane >> 4, l15 = lane & 15;
    ushort_t* P = Pl[wave];

    // Q (A-operand) and K (B-operand) fragments straight from global, rows clamped
    short8 aQ[4], bK[4];
#pragma unroll
    for (int t = 0; t < 4; ++t) {
        int row = t * 16 + l15; if (row > 48) row = 48;
        aQ[t] = *(const short8*)(qkv + (size_t)(w * 49 + row) * 1152 + h * 32 + quad * 8);
        bK[t] = *(const short8*)(qkv + (size_t)(w * 49 + row) * 1152 + 384 + h * 32 + quad * 8);
    }
    floatx4 S[4][4];
    floatx4 z4 = (floatx4){0.f, 0.f, 0.f, 0.f};
#pragma unroll
    for (int mt = 0; mt < 4; ++mt)
#pragma unroll
        for (int nt = 0; nt < 4; ++nt)
            S[mt][nt] = __builtin_amdgcn_mfma_f32_16x16x32_bf16(aQ[mt], bK[nt], z4, 0, 0, 0);

    // V^T fragments direct from global
    short8 aV[2][2];
#pragma unroll
    for (int mt = 0; mt < 2; ++mt)
#pragma unroll
        for (int kt = 0; kt < 2; ++kt) {
            short8 v;
#pragma unroll
            for (int t = 0; t < 8; ++t) {
                int j = kt * 32 + quad * 8 + t; if (j > 48) j = 48;
                v[t] = (short)qkv[(size_t)(w * 49 + j) * 1152 + 768 + h * 32 + mt * 16 + l15];
            }
            aV[mt][kt] = v;
        }

    // softmax in C-layout registers: row q = mt*16+quad*4+r, col j = nt*16+l15
    const float* bT = biasT + h * 4096;
#pragma unroll
    for (int mt = 0; mt < 4; ++mt) {
        float4 bq[4];
#pragma unroll
        for (int nt = 0; nt < 4; ++nt)
            bq[nt] = *(const float4*)(bT + (nt * 16 + l15) * 64 + mt * 16 + quad * 4);
#pragma unroll
        for (int r = 0; r < 4; ++r) {
            int q = mt * 16 + quad * 4 + r;
            int key = (q ^ (q >> 3)) & 7;
            float mx = -1e30f;
#pragma unroll
            for (int nt = 0; nt < 4; ++nt) {
                int j = nt * 16 + l15;
                float sv = S[mt][nt][r] + ((const float*)&bq[nt])[r];
                if (j >= 49) sv = -1e30f;
                S[mt][nt][r] = sv;
                mx = fmaxf(mx, sv);
            }
#pragma unroll
            for (int off = 1; off < 16; off <<= 1) mx = fmaxf(mx, __shfl_xor(mx, off, 64));
            float sum = 0.f;
#pragma unroll
            for (int nt = 0; nt < 4; ++nt) {
                int j = nt * 16 + l15;
                float p = __expf(S[mt][nt][r] - mx);
                if (j >= 49) p = 0.f;
                S[mt][nt][r] = p;
                sum += p;
            }
#pragma unroll
            for (int off = 1; off < 16; off <<= 1) sum += __shfl_xor(sum, off, 64);
            float inv = 1.f / sum;
#pragma unroll
            for (int nt = 0; nt < 4; ++nt) {
                int j = nt * 16 + l15;
                P[q * 64 + (((j >> 3) ^ key) << 3) + (j & 7)] = f2bf(S[mt][nt][r] * inv);
            }
        }
    }
    // wave-local fence: P writes (all lanes) visible before swizzled reads
    asm volatile("s_waitcnt lgkmcnt(0)" ::: "memory");
    __builtin_amdgcn_sched_barrier(0);

    // O^T = V^T @ P^T : A = aV (global), B = P[query][j] (LDS, swizzled)
    floatx4 Oc[2][4];
#pragma unroll
    for (int mt = 0; mt < 2; ++mt)
#pragma unroll
        for (int nt = 0; nt < 4; ++nt)
            Oc[mt][nt] = z4;
#pragma unroll
    for (int nt = 0; nt < 4; ++nt) {
        int query = nt * 16 + l15;
        int key = (query ^ (query >> 3)) & 7;
#pragma unroll
        for (int kt = 0; kt < 2; ++kt) {
            int slot = ((kt * 4 + quad) ^ key) & 7;
            short8 bP = *(const short8*)&P[query * 64 + slot * 8];
#pragma unroll
            for (int mt = 0; mt < 2; ++mt)
                Oc[mt][nt] = __builtin_amdgcn_mfma_f32_16x16x32_bf16(
                    aV[mt][kt], bP, Oc[mt][nt], 0, 0, 0);
        }
    }
#pragma unroll
    for (int nt = 0; nt < 4; ++nt) {
        int query = nt * 16 + l15;
        if (query < 49) {
#pragma unroll
            for (int mt = 0; mt < 2; ++mt) {
                ushort4 pk;
                pk.x = f2bf(Oc[mt][nt][0]);
                pk.y = f2bf(Oc[mt][nt][1]);
                pk.z = f2bf(Oc[mt][nt][2]);
                pk.w = f2bf(Oc[mt][nt][3]);
                *(ushort4*)(O + (size_t)(w * 49 + query) * 384 + h * 32 + mt * 16 + quad * 4) = pk;
            }
        }
    }
}

// ---------------- launcher ----------------
extern "C" void kernel_launch(void* const* d_in, const int* in_sizes, int n_in,
                              void* d_out, int out_size, void* d_ws, size_t ws_size,
                              hipStream_t stream) {
    const float* x      = (const float*)d_in[0];
    const float* n1g    = (const float*)d_in[1];
    const float* n1b    = (const float*)d_in[2];
    const float* qkv_w  = (const float*)d_in[3];
    const float* qkv_b  = (const float*)d_in[4];
    const float* proj_w = (const float*)d_in[5];
    const float* proj_b = (const float*)d_in[6];
    const float* rpb    = (const float*)d_in[7];
    const float* n2g    = (const float*)d_in[8];
    const float* n2b    = (const float*)d_in[9];
    const float* w1     = (const float*)d_in[10];
    const float* b1     = (const float*)d_in[11];
    const float* w2     = (const float*)d_in[12];
    const float* b2     = (const float*)d_in[13];
    float* out = (float*)d_out;
    char* ws = (char*)d_ws;

    // ws layout (~150.6 MB total):
    ushort_t* qkvbuf = (ushort_t*)ws;                         // 50176*1152*2 = 115,605,504 (reused for MLP hidden halves)
    ushort_t* bufA   = (ushort_t*)(ws + 115605504);           // 50176*384*2  = 38,535,168 (Xw -> O -> H2)
    ushort_t* wq     = (ushort_t*)(ws + 154140672);           // 442368
    ushort_t* wp     = wq + 442368;                           // 147456
    ushort_t* wm1    = wp + 147456;                           // 589824
    ushort_t* wm2    = wm1 + 589824;                          // 589824
    float* biasT     = (float*)(ws + 154140672 + 3538944);    // 12*64*64*4 = 196,608

    cvt_weights<<<2304, 256, 0, stream>>>(qkv_w, proj_w, w1, w2, wq, wp, wm1, wm2);
    build_bias<<<192, 256, 0, stream>>>(rpb, biasT);

    // LN1 + shift + window partition -> Xw (bufA)
    ln_kernel<true><<<12544, 256, 0, stream>>>(x, n1g, n1b, bufA);
    // QKV projection (q scaled), bf16 out: 392 bm x 9 bn
    gemm_rf<0, 384><<<3528, 256, 0, stream>>>(bufA, wq, qkv_b, qkvbuf, nullptr, 50176, 1152);
    // window attention -> O (bufA, overwrites Xw)
    attn_kernel<<<3072, 256, 0, stream>>>(qkvbuf, biasT, bufA);
    // proj + window-reverse + unshift + residual -> x1 (d_out, f32): 392 x 3
    gemm_rf<2, 384><<<1176, 256, 0, stream>>>(bufA, wp, proj_b, out, x, 50176, 384);
    // LN2 -> H2 (bufA, overwrites O)
    ln_kernel<false><<<12544, 256, 0, stream>>>(out, n2g, n2b, bufA);
    // MLP in two M-halves, hidden reuses qkvbuf
    for (int half = 0; half < 2; ++half) {
        size_t mo = (size_t)half * 25088;
        // MLP1: 196 bm x 12 bn
        gemm_rf<1, 384><<<2352, 256, 0, stream>>>(bufA + mo * 384, wm1, b1, qkvbuf, nullptr, 25088, 1536);
        // MLP2: 196 bm x 3 bn
        gemm_rf<3, 1536><<<588, 256, 0, stream>>>(qkvbuf, wm2, b2, out + mo * 384, out + mo * 384, 25088, 384);
    }
}

// Round 9
// 570.377 us; speedup vs baseline: 1.7694x; 1.7694x over previous
//
#include <hip/hip_runtime.h>

typedef unsigned short ushort_t;
typedef unsigned int uint32;
typedef __attribute__((ext_vector_type(8))) short short8;
typedef __attribute__((ext_vector_type(4))) float floatx4;

static __device__ __forceinline__ ushort_t f2bf(float f) {
    union { float f; unsigned int u; } c; c.f = f;
    unsigned int u = c.u;
    return (ushort_t)((u + 0x7FFFu + ((u >> 16) & 1u)) >> 16);
}
static __device__ __forceinline__ float bf2f(uint32 us) {
    union { unsigned int u; float f; } c; c.u = us << 16; return c.f;
}

// XOR-swizzled LDS offset (ushorts) for [row][64-ushort] tiles staged as 8x16B slots.
static __device__ __forceinline__ int swz_off(int row, int slot16) {
    return row * 64 + (((slot16 ^ (row & 7)) & 7) << 3);
}

// ---------------- weight f32 -> bf16 conversion ----------------
__global__ __launch_bounds__(256) void cvt_weights(
    const float* __restrict__ w0, const float* __restrict__ w1,
    const float* __restrict__ w2, const float* __restrict__ w3,
    ushort_t* __restrict__ o0, ushort_t* __restrict__ o1,
    ushort_t* __restrict__ o2, ushort_t* __restrict__ o3)
{
    int i = blockIdx.x * 256 + threadIdx.x;
    if (i < 442368) o0[i] = f2bf(w0[i]);   // qkv_w [1152,384]
    if (i < 147456) o1[i] = f2bf(w1[i]);   // proj_w [384,384]
    if (i < 589824) o2[i] = f2bf(w2[i]);   // mlp_w1 [1536,384]
    if (i < 589824) o3[i] = f2bf(w3[i]);   // mlp_w2 [384,1536]
}

// ---------------- rel-pos bias, TRANSPOSED: biasT[h][j(key)][q(query)] f32 ----
__global__ __launch_bounds__(256) void build_bias(
    const float* __restrict__ rpb, float* __restrict__ biasT)
{
    int idx = blockIdx.x * 256 + threadIdx.x;   // < 12*64*64 = 49152
    int h = idx >> 12, j = (idx >> 6) & 63, q = idx & 63;
    float v = 0.f;
    if (q < 49 && j < 49) {
        int pi = q / 7, pj = q - pi * 7;        // query coords
        int qi = j / 7, qj = j - qi * 7;        // key coords
        v = rpb[((pi - qi + 6) * 13 + (pj - qj + 6)) * 12 + h];
    }
    biasT[idx] = v;   // [h][j][q]
}

// ---------------- LN1 (one wave per token), fuses roll+window partition ------
__global__ __launch_bounds__(256) void ln_kernel(
    const float* __restrict__ x, const float* __restrict__ g,
    const float* __restrict__ b, ushort_t* __restrict__ out)
{
    int wave = threadIdx.x >> 6, lane = threadIdx.x & 63;
    int tkn = blockIdx.x * 4 + wave;       // output row M (0..50175)
    int w = tkn / 49, n = tkn - w * 49;
    int bb = w >> 6, wrem = w & 63;
    int wi = wrem >> 3, wj = wrem & 7;
    int pi = n / 7, pj = n - pi * 7;
    int si = wi * 7 + pi + 3; if (si >= 56) si -= 56;   // roll(-3): gather at +3
    int sj = wj * 7 + pj + 3; if (sj >= 56) sj -= 56;
    const float* src = x + ((size_t)bb * 3136 + si * 56 + sj) * 384;
    float v[6];
    float s = 0.f, sq = 0.f;
#pragma unroll
    for (int it = 0; it < 3; ++it) {
        float2 t = *(const float2*)(src + it * 128 + lane * 2);
        v[it * 2] = t.x; v[it * 2 + 1] = t.y;
        s += t.x + t.y; sq += t.x * t.x + t.y * t.y;
    }
#pragma unroll
    for (int off = 32; off; off >>= 1) {
        s += __shfl_xor(s, off, 64);
        sq += __shfl_xor(sq, off, 64);
    }
    float mean = s * (1.f / 384.f);
    float rstd = rsqrtf(sq * (1.f / 384.f) - mean * mean + 1e-5f);
    ushort_t* dst = out + (size_t)tkn * 384;
#pragma unroll
    for (int it = 0; it < 3; ++it) {
        int c = it * 128 + lane * 2;
        float2 gg = *(const float2*)(g + c);
        float2 bb2 = *(const float2*)(b + c);
        float y0 = (v[it * 2] - mean) * rstd * gg.x + bb2.x;
        float y1 = (v[it * 2 + 1] - mean) * rstd * gg.y + bb2.y;
        uint32 pack = ((uint32)f2bf(y0)) | (((uint32)f2bf(y1)) << 16);
        *(uint32*)(dst + c) = pack;
    }
}

// ---------------- fused residual + LN2 (replaces scatter epilogue + LN2) ------
// Per output token t: gather proj-out row via INVERSE window map (row-contiguous
// 768B read), x1 = x + po -> d_out (f32); LN(x1) -> h2 (bf16).
__global__ __launch_bounds__(256) void resid_ln(
    const float* __restrict__ x, const ushort_t* __restrict__ po,
    const float* __restrict__ g, const float* __restrict__ b,
    float* __restrict__ x1, ushort_t* __restrict__ h2)
{
    int wave = threadIdx.x >> 6, lane = threadIdx.x & 63;
    int tkn = blockIdx.x * 4 + wave;       // 0..50175, output (spatial) order
    int bb = tkn / 3136, rem = tkn - bb * 3136;
    int i = rem / 56, j = rem - i * 56;
    int u = i + 53; if (u >= 56) u -= 56;  // (i-3) mod 56
    int v2 = j + 53; if (v2 >= 56) v2 -= 56;
    int wi = u / 7, pi = u - wi * 7;
    int wj = v2 / 7, pj = v2 - wj * 7;
    size_t wt = (size_t)((bb * 64 + wi * 8 + wj) * 49 + pi * 7 + pj);
    const float* xs = x + (size_t)tkn * 384;
    const ushort_t* ps = po + wt * 384;
    float v[6];
    float s = 0.f, sq = 0.f;
#pragma unroll
    for (int it = 0; it < 3; ++it) {
        float2 t = *(const float2*)(xs + it * 128 + lane * 2);
        uint32 pp = *(const uint32*)(ps + it * 128 + lane * 2);
        float a0 = t.x + bf2f(pp & 0xffffu);
        float a1 = t.y + bf2f(pp >> 16);
        v[it * 2] = a0; v[it * 2 + 1] = a1;
        s += a0 + a1; sq += a0 * a0 + a1 * a1;
    }
#pragma unroll
    for (int off = 32; off; off >>= 1) {
        s += __shfl_xor(s, off, 64);
        sq += __shfl_xor(sq, off, 64);
    }
    float mean = s * (1.f / 384.f);
    float rstd = rsqrtf(sq * (1.f / 384.f) - mean * mean + 1e-5f);
    float* xd = x1 + (size_t)tkn * 384;
    ushort_t* hd = h2 + (size_t)tkn * 384;
#pragma unroll
    for (int it = 0; it < 3; ++it) {
        int c = it * 128 + lane * 2;
        float2 w2; w2.x = v[it * 2]; w2.y = v[it * 2 + 1];
        *(float2*)(xd + c) = w2;
        float2 gg = *(const float2*)(g + c);
        float2 bb2 = *(const float2*)(b + c);
        float y0 = (v[it * 2] - mean) * rstd * gg.x + bb2.x;
        float y1 = (v[it * 2 + 1] - mean) * rstd * gg.y + bb2.y;
        uint32 pack = ((uint32)f2bf(y0)) | (((uint32)f2bf(y1)) << 16);
        *(uint32*)(hd + c) = pack;
    }
}

// ---------------- bf16 GEMM: Y = A[M,K] @ Bw[N,K]^T ----------------
// 128x128 tile, BK=64, DEPTH-2 reg-staged pipeline (round 6/7 structure).
// EPI 0: +bias, scale q cols, bf16 out (QKV)
// EPI 1: +bias, exact GELU, bf16 out (MLP1)
// EPI 3: +bias, +resid (sequential), f32 out (MLP2, N=384)
// EPI 4: +bias, bf16 out (PROJ -> window-order buffer)
template<int EPI>
__global__ __launch_bounds__(256, 2) void gemm_bt(
    const ushort_t* __restrict__ A, const ushort_t* __restrict__ Bw,
    const float* __restrict__ bias, void* __restrict__ out,
    const float* __restrict__ resid, int M, int N, int K)
{
    __shared__ __align__(16) ushort_t As[2][128 * 64];   // 2 x 16 KB
    __shared__ __align__(16) ushort_t Bs[2][128 * 64];   // 2 x 16 KB
    int tid = threadIdx.x;

    // bijective XCD-chunked swizzle (m204)
    int nwg = gridDim.x;
    int orig = blockIdx.x;
    int xcd = orig & 7, lid = orig >> 3;
    int q8 = nwg >> 3, r8 = nwg & 7;
    int swz = (xcd < r8 ? xcd * (q8 + 1) : r8 * (q8 + 1) + (xcd - r8) * q8) + lid;
    int bnT = N >> 7;
    int bm = swz / bnT, bn = swz - bm * bnT;

    int wv = tid >> 6, lane = tid & 63;
    int wr = wv >> 1, wc = wv & 1;               // 2x2 waves, 64x64 out each
    int quad = lane >> 4, l15 = lane & 15;
    int r0 = tid >> 3, s0 = tid & 7;             // staging: 32 row-threads x 8 slots

    floatx4 acc[4][4];
#pragma unroll
    for (int mi = 0; mi < 4; ++mi)
#pragma unroll
        for (int ni = 0; ni < 4; ++ni)
            acc[mi][ni] = (floatx4){0.f, 0.f, 0.f, 0.f};

    const ushort_t* Ar0 = A + (size_t)(bm * 128 + r0) * K + s0 * 8;
    const ushort_t* Ar1 = Ar0 + (size_t)32 * K;
    const ushort_t* Ar2 = Ar0 + (size_t)64 * K;
    const ushort_t* Ar3 = Ar0 + (size_t)96 * K;
    const ushort_t* Br0 = Bw + (size_t)(bn * 128 + r0) * K + s0 * 8;
    const ushort_t* Br1 = Br0 + (size_t)32 * K;
    const ushort_t* Br2 = Br0 + (size_t)64 * K;
    const ushort_t* Br3 = Br0 + (size_t)96 * K;

    // swizzled ds_write offsets (fixed per thread)
    int w0 = swz_off(r0, s0), w1 = swz_off(r0 + 32, s0);
    int w2 = swz_off(r0 + 64, s0), w3 = swz_off(r0 + 96, s0);

#define GLOAD(a0,a1,a2,a3,b0,b1,b2,b3,k0) \
    a0 = *(const uint4*)(Ar0 + (k0)); a1 = *(const uint4*)(Ar1 + (k0)); \
    a2 = *(const uint4*)(Ar2 + (k0)); a3 = *(const uint4*)(Ar3 + (k0)); \
    b0 = *(const uint4*)(Br0 + (k0)); b1 = *(const uint4*)(Br1 + (k0)); \
    b2 = *(const uint4*)(Br2 + (k0)); b3 = *(const uint4*)(Br3 + (k0));

#define SWRITE(buf,a0,a1,a2,a3,b0,b1,b2,b3) \
    *(uint4*)&As[buf][w0] = a0; *(uint4*)&As[buf][w1] = a1; \
    *(uint4*)&As[buf][w2] = a2; *(uint4*)&As[buf][w3] = a3; \
    *(uint4*)&Bs[buf][w0] = b0; *(uint4*)&Bs[buf][w1] = b1; \
    *(uint4*)&Bs[buf][w2] = b2; *(uint4*)&Bs[buf][w3] = b3;

#define COMPUTE(buf) \
    _Pragma("unroll") \
    for (int kk = 0; kk < 64; kk += 32) { \
        short8 af[4], bfr[4]; \
        _Pragma("unroll") \
        for (int mi = 0; mi < 4; ++mi) \
            af[mi] = *(const short8*)&As[buf][swz_off(wr * 64 + mi * 16 + l15, (kk >> 3) + quad)]; \
        _Pragma("unroll") \
        for (int ni = 0; ni < 4; ++ni) \
            bfr[ni] = *(const short8*)&Bs[buf][swz_off(wc * 64 + ni * 16 + l15, (kk >> 3) + quad)]; \
        _Pragma("unroll") \
        for (int mi = 0; mi < 4; ++mi) \
            _Pragma("unroll") \
            for (int ni = 0; ni < 4; ++ni) \
                acc[mi][ni] = __builtin_amdgcn_mfma_f32_16x16x32_bf16( \
                    af[mi], bfr[ni], acc[mi][ni], 0, 0, 0); \
    }

    int nK = K >> 6;   // even (6 or 24)
    uint4 pa0, pa1, pa2, pa3, pb0, pb1, pb2, pb3;   // staging set P
    uint4 qa0, qa1, qa2, qa3, qb0, qb1, qb2, qb3;   // staging set Q

    // prologue: P = tile0, Q = tile1; write tile0 -> buf0; re-issue P = tile2
    GLOAD(pa0, pa1, pa2, pa3, pb0, pb1, pb2, pb3, 0);
    GLOAD(qa0, qa1, qa2, qa3, qb0, qb1, qb2, qb3, 64);
    SWRITE(0, pa0, pa1, pa2, pa3, pb0, pb1, pb2, pb3);
    if (nK > 2) { GLOAD(pa0, pa1, pa2, pa3, pb0, pb1, pb2, pb3, 128); }
    __syncthreads();   // buf0 ready

    for (int kt = 0; kt < nK; kt += 2) {
        // ---- phase 1: compute tile kt from buf0 ----
        COMPUTE(0);
        SWRITE(1, qa0, qa1, qa2, qa3, qb0, qb1, qb2, qb3);
        if (kt + 3 < nK) { int k0 = (kt + 3) << 6; GLOAD(qa0, qa1, qa2, qa3, qb0, qb1, qb2, qb3, k0); }
        __syncthreads();   // buf1 ready; everyone done with buf0
        // ---- phase 2: compute tile kt+1 from buf1 ----
        COMPUTE(1);
        if (kt + 2 < nK) {
            SWRITE(0, pa0, pa1, pa2, pa3, pb0, pb1, pb2, pb3);
            if (kt + 4 < nK) { int k0 = (kt + 4) << 6; GLOAD(pa0, pa1, pa2, pa3, pb0, pb1, pb2, pb3, k0); }
            __syncthreads();   // buf0 ready; everyone done with buf1
        }
    }
#undef GLOAD
#undef SWRITE
#undef COMPUTE

#pragma unroll
    for (int mi = 0; mi < 4; ++mi) {
#pragma unroll
        for (int ni = 0; ni < 4; ++ni) {
            int gn = bn * 128 + wc * 64 + ni * 16 + l15;
            float bv = bias[gn];
#pragma unroll
            for (int r = 0; r < 4; ++r) {
                int gm = bm * 128 + wr * 64 + mi * 16 + quad * 4 + r;
                float v = acc[mi][ni][r] + bv;
                if (EPI == 0) {
                    if (gn < 384) v *= 0.17677669529663689f;   // hd^-0.5 on q
                    ((ushort_t*)out)[(size_t)gm * N + gn] = f2bf(v);
                } else if (EPI == 1) {
                    v = 0.5f * v * (1.f + erff(v * 0.70710678118654752f));
                    ((ushort_t*)out)[(size_t)gm * N + gn] = f2bf(v);
                } else if (EPI == 4) {
                    ((ushort_t*)out)[(size_t)gm * N + gn] = f2bf(v);
                } else {
                    size_t dst = (size_t)gm * 384 + gn;
                    ((float*)out)[dst] = resid[dst] + v;
                }
            }
        }
    }
}

// ---------------- window attention v2 (round 7, kept): no barriers ------------
__global__ __launch_bounds__(256) void attn_kernel(
    const ushort_t* __restrict__ qkv,   // [50176,1152] bf16 (q pre-scaled)
    const float* __restrict__ biasT,    // [12][64 j][64 q] f32
    ushort_t* __restrict__ O)           // [50176,384] bf16
{
    __shared__ __align__(16) ushort_t Pl[4][64 * 64];   // 32 KB
    int wave = threadIdx.x >> 6;
    int lane = threadIdx.x & 63;
    int id = blockIdx.x * 4 + wave;     // 0..12287
    int w = id / 12, h = id % 12;
    int quad = lane >> 4, l15 = lane & 15;
    ushort_t* P = Pl[wave];

    short8 aQ[4], bK[4];
#pragma unroll
    for (int t = 0; t < 4; ++t) {
        int row = t * 16 + l15; if (row > 48) row = 48;
        aQ[t] = *(const short8*)(qkv + (size_t)(w * 49 + row) * 1152 + h * 32 + quad * 8);
        bK[t] = *(const short8*)(qkv + (size_t)(w * 49 + row) * 1152 + 384 + h * 32 + quad * 8);
    }
    floatx4 S[4][4];
    floatx4 z4 = (floatx4){0.f, 0.f, 0.f, 0.f};
#pragma unroll
    for (int mt = 0; mt < 4; ++mt)
#pragma unroll
        for (int nt = 0; nt < 4; ++nt)
            S[mt][nt] = __builtin_amdgcn_mfma_f32_16x16x32_bf16(aQ[mt], bK[nt], z4, 0, 0, 0);

    short8 aV[2][2];
#pragma unroll
    for (int mt = 0; mt < 2; ++mt)
#pragma unroll
        for (int kt = 0; kt < 2; ++kt) {
            short8 v;
#pragma unroll
            for (int t = 0; t < 8; ++t) {
                int j = kt * 32 + quad * 8 + t; if (j > 48) j = 48;
                v[t] = (short)qkv[(size_t)(w * 49 + j) * 1152 + 768 + h * 32 + mt * 16 + l15];
            }
            aV[mt][kt] = v;
        }

    const float* bT = biasT + h * 4096;
#pragma unroll
    for (int mt = 0; mt < 4; ++mt) {
        float4 bq[4];
#pragma unroll
        for (int nt = 0; nt < 4; ++nt)
            bq[nt] = *(const float4*)(bT + (nt * 16 + l15) * 64 + mt * 16 + quad * 4);
#pragma unroll
        for (int r = 0; r < 4; ++r) {
            int q = mt * 16 + quad * 4 + r;
            int key = (q ^ (q >> 3)) & 7;
            float mx = -1e30f;
#pragma unroll
            for (int nt = 0; nt < 4; ++nt) {
                int j = nt * 16 + l15;
                float sv = S[mt][nt][r] + ((const float*)&bq[nt])[r];
                if (j >= 49) sv = -1e30f;
                S[mt][nt][r] = sv;
                mx = fmaxf(mx, sv);
            }
#pragma unroll
            for (int off = 1; off < 16; off <<= 1) mx = fmaxf(mx, __shfl_xor(mx, off, 64));
            float sum = 0.f;
#pragma unroll
            for (int nt = 0; nt < 4; ++nt) {
                int j = nt * 16 + l15;
                float p = __expf(S[mt][nt][r] - mx);
                if (j >= 49) p = 0.f;
                S[mt][nt][r] = p;
                sum += p;
            }
#pragma unroll
            for (int off = 1; off < 16; off <<= 1) sum += __shfl_xor(sum, off, 64);
            float inv = 1.f / sum;
#pragma unroll
            for (int nt = 0; nt < 4; ++nt) {
                int j = nt * 16 + l15;
                P[q * 64 + (((j >> 3) ^ key) << 3) + (j & 7)] = f2bf(S[mt][nt][r] * inv);
            }
        }
    }
    asm volatile("s_waitcnt lgkmcnt(0)" ::: "memory");
    __builtin_amdgcn_sched_barrier(0);

    floatx4 Oc[2][4];
#pragma unroll
    for (int mt = 0; mt < 2; ++mt)
#pragma unroll
        for (int nt = 0; nt < 4; ++nt)
            Oc[mt][nt] = z4;
#pragma unroll
    for (int nt = 0; nt < 4; ++nt) {
        int query = nt * 16 + l15;
        int key = (query ^ (query >> 3)) & 7;
#pragma unroll
        for (int kt = 0; kt < 2; ++kt) {
            int slot = ((kt * 4 + quad) ^ key) & 7;
            short8 bP = *(const short8*)&P[query * 64 + slot * 8];
#pragma unroll
            for (int mt = 0; mt < 2; ++mt)
                Oc[mt][nt] = __builtin_amdgcn_mfma_f32_16x16x32_bf16(
                    aV[mt][kt], bP, Oc[mt][nt], 0, 0, 0);
        }
    }
#pragma unroll
    for (int nt = 0; nt < 4; ++nt) {
        int query = nt * 16 + l15;
        if (query < 49) {
#pragma unroll
            for (int mt = 0; mt < 2; ++mt) {
                ushort4 pk;
                pk.x = f2bf(Oc[mt][nt][0]);
                pk.y = f2bf(Oc[mt][nt][1]);
                pk.z = f2bf(Oc[mt][nt][2]);
                pk.w = f2bf(Oc[mt][nt][3]);
                *(ushort4*)(O + (size_t)(w * 49 + query) * 384 + h * 32 + mt * 16 + quad * 4) = pk;
            }
        }
    }
}

// ---------------- launcher ----------------
extern "C" void kernel_launch(void* const* d_in, const int* in_sizes, int n_in,
                              void* d_out, int out_size, void* d_ws, size_t ws_size,
                              hipStream_t stream) {
    const float* x      = (const float*)d_in[0];
    const float* n1g    = (const float*)d_in[1];
    const float* n1b    = (const float*)d_in[2];
    const float* qkv_w  = (const float*)d_in[3];
    const float* qkv_b  = (const float*)d_in[4];
    const float* proj_w = (const float*)d_in[5];
    const float* proj_b = (const float*)d_in[6];
    const float* rpb    = (const float*)d_in[7];
    const float* n2g    = (const float*)d_in[8];
    const float* n2b    = (const float*)d_in[9];
    const float* w1     = (const float*)d_in[10];
    const float* b1     = (const float*)d_in[11];
    const float* w2     = (const float*)d_in[12];
    const float* b2     = (const float*)d_in[13];
    float* out = (float*)d_out;
    char* ws = (char*)d_ws;

    // ws layout (~150.6 MB total):
    ushort_t* qkvbuf = (ushort_t*)ws;                         // 50176*1152*2 (qkv -> Po -> MLP hidden)
    ushort_t* bufA   = (ushort_t*)(ws + 115605504);           // 50176*384*2  (Xw -> O -> H2)
    ushort_t* wq     = (ushort_t*)(ws + 154140672);           // 442368
    ushort_t* wp     = wq + 442368;                           // 147456
    ushort_t* wm1    = wp + 147456;                           // 589824
    ushort_t* wm2    = wm1 + 589824;                          // 589824
    float* biasT     = (float*)(ws + 154140672 + 3538944);    // 12*64*64*4

    cvt_weights<<<2304, 256, 0, stream>>>(qkv_w, proj_w, w1, w2, wq, wp, wm1, wm2);
    build_bias<<<192, 256, 0, stream>>>(rpb, biasT);

    // LN1 + shift + window partition -> Xw (bufA)
    ln_kernel<<<12544, 256, 0, stream>>>(x, n1g, n1b, bufA);
    // QKV projection (q scaled), bf16 out: 392 bm x 9 bn
    gemm_bt<0><<<3528, 256, 0, stream>>>(bufA, wq, qkv_b, qkvbuf, nullptr, 50176, 1152, 384);
    // window attention -> O (bufA, overwrites Xw)
    attn_kernel<<<3072, 256, 0, stream>>>(qkvbuf, biasT, bufA);
    // proj (+bias, bf16, window order) -> Po (qkvbuf reuse): 392 x 3
    gemm_bt<4><<<1176, 256, 0, stream>>>(bufA, wp, proj_b, qkvbuf, nullptr, 50176, 384, 384);
    // fused: x1 = x + window_reverse(Po) -> d_out (f32); LN2(x1) -> H2 (bufA)
    resid_ln<<<12544, 256, 0, stream>>>(x, qkvbuf, n2g, n2b, out, bufA);
    // MLP in two M-halves, hidden reuses qkvbuf (Po already consumed)
    for (int half = 0; half < 2; ++half) {
        size_t mo = (size_t)half * 25088;
        // MLP1: 196 bm x 12 bn
        gemm_bt<1><<<2352, 256, 0, stream>>>(bufA + mo * 384, wm1, b1, qkvbuf, nullptr, 25088, 1536, 384);
        // MLP2: 196 bm x 3 bn
        gemm_bt<3><<<588, 256, 0, stream>>>(qkvbuf, wm2, b2, out + mo * 384, out + mo * 384, 25088, 384, 1536);
    }
}

// Round 10
// 555.465 us; speedup vs baseline: 1.8169x; 1.0268x over previous
//
#include <hip/hip_runtime.h>

typedef unsigned short ushort_t;
typedef unsigned int uint32;
typedef __attribute__((ext_vector_type(8))) short short8;
typedef __attribute__((ext_vector_type(4))) float floatx4;

static __device__ __forceinline__ ushort_t f2bf(float f) {
    union { float f; unsigned int u; } c; c.f = f;
    unsigned int u = c.u;
    return (ushort_t)((u + 0x7FFFu + ((u >> 16) & 1u)) >> 16);
}
static __device__ __forceinline__ float bf2f(uint32 us) {
    union { unsigned int u; float f; } c; c.u = us << 16; return c.f;
}

// exact-GELU via Abramowitz-Stegun 7.1.26 erf (|err| <= 1.5e-7, far below bf16
// output quantization). ~15 VALU vs ~40+ for libm erff -- the MLP1 epilogue
// was erff-bound (round 9: 1.57x per-block vs identical-K QKV).
static __device__ __forceinline__ float fast_gelu(float v) {
    float x = v * 0.70710678118654752f;
    float ax = __builtin_fabsf(x);
    float t = __builtin_amdgcn_rcpf(__builtin_fmaf(0.3275911f, ax, 1.f));
    float p = __builtin_fmaf(1.061405429f, t, -1.453152027f);
    p = __builtin_fmaf(p, t, 1.421413741f);
    p = __builtin_fmaf(p, t, -0.284496736f);
    p = __builtin_fmaf(p, t, 0.254829592f);
    p = p * t;
    float e = __expf(-x * x);
    float erfabs = __builtin_fmaf(-p, e, 1.f);
    float er = __builtin_copysignf(erfabs, x);
    return v * __builtin_fmaf(0.5f, er, 0.5f);
}

// XOR-swizzled LDS offset (ushorts) for [row][64-ushort] tiles staged as 8x16B slots.
static __device__ __forceinline__ int swz_off(int row, int slot16) {
    return row * 64 + (((slot16 ^ (row & 7)) & 7) << 3);
}

// ---------------- weight f32 -> bf16 conversion ----------------
__global__ __launch_bounds__(256) void cvt_weights(
    const float* __restrict__ w0, const float* __restrict__ w1,
    const float* __restrict__ w2, const float* __restrict__ w3,
    ushort_t* __restrict__ o0, ushort_t* __restrict__ o1,
    ushort_t* __restrict__ o2, ushort_t* __restrict__ o3)
{
    int i = blockIdx.x * 256 + threadIdx.x;
    if (i < 442368) o0[i] = f2bf(w0[i]);   // qkv_w [1152,384]
    if (i < 147456) o1[i] = f2bf(w1[i]);   // proj_w [384,384]
    if (i < 589824) o2[i] = f2bf(w2[i]);   // mlp_w1 [1536,384]
    if (i < 589824) o3[i] = f2bf(w3[i]);   // mlp_w2 [384,1536]
}

// ---------------- rel-pos bias, TRANSPOSED: biasT[h][j(key)][q(query)] f32 ----
__global__ __launch_bounds__(256) void build_bias(
    const float* __restrict__ rpb, float* __restrict__ biasT)
{
    int idx = blockIdx.x * 256 + threadIdx.x;   // < 12*64*64 = 49152
    int h = idx >> 12, j = (idx >> 6) & 63, q = idx & 63;
    float v = 0.f;
    if (q < 49 && j < 49) {
        int pi = q / 7, pj = q - pi * 7;        // query coords
        int qi = j / 7, qj = j - qi * 7;        // key coords
        v = rpb[((pi - qi + 6) * 13 + (pj - qj + 6)) * 12 + h];
    }
    biasT[idx] = v;   // [h][j][q]
}

// ---------------- LN1 (one wave per token), fuses roll+window partition ------
__global__ __launch_bounds__(256) void ln_kernel(
    const float* __restrict__ x, const float* __restrict__ g,
    const float* __restrict__ b, ushort_t* __restrict__ out)
{
    int wave = threadIdx.x >> 6, lane = threadIdx.x & 63;
    int tkn = blockIdx.x * 4 + wave;       // output row M (0..50175)
    int w = tkn / 49, n = tkn - w * 49;
    int bb = w >> 6, wrem = w & 63;
    int wi = wrem >> 3, wj = wrem & 7;
    int pi = n / 7, pj = n - pi * 7;
    int si = wi * 7 + pi + 3; if (si >= 56) si -= 56;   // roll(-3): gather at +3
    int sj = wj * 7 + pj + 3; if (sj >= 56) sj -= 56;
    const float* src = x + ((size_t)bb * 3136 + si * 56 + sj) * 384;
    float v[6];
    float s = 0.f, sq = 0.f;
#pragma unroll
    for (int it = 0; it < 3; ++it) {
        float2 t = *(const float2*)(src + it * 128 + lane * 2);
        v[it * 2] = t.x; v[it * 2 + 1] = t.y;
        s += t.x + t.y; sq += t.x * t.x + t.y * t.y;
    }
#pragma unroll
    for (int off = 32; off; off >>= 1) {
        s += __shfl_xor(s, off, 64);
        sq += __shfl_xor(sq, off, 64);
    }
    float mean = s * (1.f / 384.f);
    float rstd = rsqrtf(sq * (1.f / 384.f) - mean * mean + 1e-5f);
    ushort_t* dst = out + (size_t)tkn * 384;
#pragma unroll
    for (int it = 0; it < 3; ++it) {
        int c = it * 128 + lane * 2;
        float2 gg = *(const float2*)(g + c);
        float2 bb2 = *(const float2*)(b + c);
        float y0 = (v[it * 2] - mean) * rstd * gg.x + bb2.x;
        float y1 = (v[it * 2 + 1] - mean) * rstd * gg.y + bb2.y;
        uint32 pack = ((uint32)f2bf(y0)) | (((uint32)f2bf(y1)) << 16);
        *(uint32*)(dst + c) = pack;
    }
}

// ---------------- fused residual + LN2 (replaces scatter epilogue + LN2) ------
__global__ __launch_bounds__(256) void resid_ln(
    const float* __restrict__ x, const ushort_t* __restrict__ po,
    const float* __restrict__ g, const float* __restrict__ b,
    float* __restrict__ x1, ushort_t* __restrict__ h2)
{
    int wave = threadIdx.x >> 6, lane = threadIdx.x & 63;
    int tkn = blockIdx.x * 4 + wave;       // 0..50175, output (spatial) order
    int bb = tkn / 3136, rem = tkn - bb * 3136;
    int i = rem / 56, j = rem - i * 56;
    int u = i + 53; if (u >= 56) u -= 56;  // (i-3) mod 56
    int v2 = j + 53; if (v2 >= 56) v2 -= 56;
    int wi = u / 7, pi = u - wi * 7;
    int wj = v2 / 7, pj = v2 - wj * 7;
    size_t wt = (size_t)((bb * 64 + wi * 8 + wj) * 49 + pi * 7 + pj);
    const float* xs = x + (size_t)tkn * 384;
    const ushort_t* ps = po + wt * 384;
    float v[6];
    float s = 0.f, sq = 0.f;
#pragma unroll
    for (int it = 0; it < 3; ++it) {
        float2 t = *(const float2*)(xs + it * 128 + lane * 2);
        uint32 pp = *(const uint32*)(ps + it * 128 + lane * 2);
        float a0 = t.x + bf2f(pp & 0xffffu);
        float a1 = t.y + bf2f(pp >> 16);
        v[it * 2] = a0; v[it * 2 + 1] = a1;
        s += a0 + a1; sq += a0 * a0 + a1 * a1;
    }
#pragma unroll
    for (int off = 32; off; off >>= 1) {
        s += __shfl_xor(s, off, 64);
        sq += __shfl_xor(sq, off, 64);
    }
    float mean = s * (1.f / 384.f);
    float rstd = rsqrtf(sq * (1.f / 384.f) - mean * mean + 1e-5f);
    float* xd = x1 + (size_t)tkn * 384;
    ushort_t* hd = h2 + (size_t)tkn * 384;
#pragma unroll
    for (int it = 0; it < 3; ++it) {
        int c = it * 128 + lane * 2;
        float2 w2; w2.x = v[it * 2]; w2.y = v[it * 2 + 1];
        *(float2*)(xd + c) = w2;
        float2 gg = *(const float2*)(g + c);
        float2 bb2 = *(const float2*)(b + c);
        float y0 = (v[it * 2] - mean) * rstd * gg.x + bb2.x;
        float y1 = (v[it * 2 + 1] - mean) * rstd * gg.y + bb2.y;
        uint32 pack = ((uint32)f2bf(y0)) | (((uint32)f2bf(y1)) << 16);
        *(uint32*)(hd + c) = pack;
    }
}

// ---------------- bf16 GEMM: Y = A[M,K] @ Bw[N,K]^T ----------------
// 128x128 tile, BK=64, DEPTH-2 reg-staged pipeline (round 6/7 structure).
// EPI 0: +bias, scale q cols, bf16 out (QKV)
// EPI 1: +bias, fast exact-GELU, bf16 out (MLP1)
// EPI 3: +bias, +resid (sequential), f32 out (MLP2, N=384)
// EPI 4: +bias, bf16 out (PROJ -> window-order buffer)
template<int EPI>
__global__ __launch_bounds__(256, 2) void gemm_bt(
    const ushort_t* __restrict__ A, const ushort_t* __restrict__ Bw,
    const float* __restrict__ bias, void* __restrict__ out,
    const float* __restrict__ resid, int M, int N, int K)
{
    __shared__ __align__(16) ushort_t As[2][128 * 64];   // 2 x 16 KB
    __shared__ __align__(16) ushort_t Bs[2][128 * 64];   // 2 x 16 KB
    int tid = threadIdx.x;

    // bijective XCD-chunked swizzle (m204)
    int nwg = gridDim.x;
    int orig = blockIdx.x;
    int xcd = orig & 7, lid = orig >> 3;
    int q8 = nwg >> 3, r8 = nwg & 7;
    int swz = (xcd < r8 ? xcd * (q8 + 1) : r8 * (q8 + 1) + (xcd - r8) * q8) + lid;
    int bnT = N >> 7;
    int bm = swz / bnT, bn = swz - bm * bnT;

    int wv = tid >> 6, lane = tid & 63;
    int wr = wv >> 1, wc = wv & 1;               // 2x2 waves, 64x64 out each
    int quad = lane >> 4, l15 = lane & 15;
    int r0 = tid >> 3, s0 = tid & 7;             // staging: 32 row-threads x 8 slots

    floatx4 acc[4][4];
#pragma unroll
    for (int mi = 0; mi < 4; ++mi)
#pragma unroll
        for (int ni = 0; ni < 4; ++ni)
            acc[mi][ni] = (floatx4){0.f, 0.f, 0.f, 0.f};

    const ushort_t* Ar0 = A + (size_t)(bm * 128 + r0) * K + s0 * 8;
    const ushort_t* Ar1 = Ar0 + (size_t)32 * K;
    const ushort_t* Ar2 = Ar0 + (size_t)64 * K;
    const ushort_t* Ar3 = Ar0 + (size_t)96 * K;
    const ushort_t* Br0 = Bw + (size_t)(bn * 128 + r0) * K + s0 * 8;
    const ushort_t* Br1 = Br0 + (size_t)32 * K;
    const ushort_t* Br2 = Br0 + (size_t)64 * K;
    const ushort_t* Br3 = Br0 + (size_t)96 * K;

    // swizzled ds_write offsets (fixed per thread)
    int w0 = swz_off(r0, s0), w1 = swz_off(r0 + 32, s0);
    int w2 = swz_off(r0 + 64, s0), w3 = swz_off(r0 + 96, s0);

#define GLOAD(a0,a1,a2,a3,b0,b1,b2,b3,k0) \
    a0 = *(const uint4*)(Ar0 + (k0)); a1 = *(const uint4*)(Ar1 + (k0)); \
    a2 = *(const uint4*)(Ar2 + (k0)); a3 = *(const uint4*)(Ar3 + (k0)); \
    b0 = *(const uint4*)(Br0 + (k0)); b1 = *(const uint4*)(Br1 + (k0)); \
    b2 = *(const uint4*)(Br2 + (k0)); b3 = *(const uint4*)(Br3 + (k0));

#define SWRITE(buf,a0,a1,a2,a3,b0,b1,b2,b3) \
    *(uint4*)&As[buf][w0] = a0; *(uint4*)&As[buf][w1] = a1; \
    *(uint4*)&As[buf][w2] = a2; *(uint4*)&As[buf][w3] = a3; \
    *(uint4*)&Bs[buf][w0] = b0; *(uint4*)&Bs[buf][w1] = b1; \
    *(uint4*)&Bs[buf][w2] = b2; *(uint4*)&Bs[buf][w3] = b3;

#define COMPUTE(buf) \
    _Pragma("unroll") \
    for (int kk = 0; kk < 64; kk += 32) { \
        short8 af[4], bfr[4]; \
        _Pragma("unroll") \
        for (int mi = 0; mi < 4; ++mi) \
            af[mi] = *(const short8*)&As[buf][swz_off(wr * 64 + mi * 16 + l15, (kk >> 3) + quad)]; \
        _Pragma("unroll") \
        for (int ni = 0; ni < 4; ++ni) \
            bfr[ni] = *(const short8*)&Bs[buf][swz_off(wc * 64 + ni * 16 + l15, (kk >> 3) + quad)]; \
        _Pragma("unroll") \
        for (int mi = 0; mi < 4; ++mi) \
            _Pragma("unroll") \
            for (int ni = 0; ni < 4; ++ni) \
                acc[mi][ni] = __builtin_amdgcn_mfma_f32_16x16x32_bf16( \
                    af[mi], bfr[ni], acc[mi][ni], 0, 0, 0); \
    }

    int nK = K >> 6;   // even (6 or 24)
    uint4 pa0, pa1, pa2, pa3, pb0, pb1, pb2, pb3;   // staging set P
    uint4 qa0, qa1, qa2, qa3, qb0, qb1, qb2, qb3;   // staging set Q

    // prologue: P = tile0, Q = tile1; write tile0 -> buf0; re-issue P = tile2
    GLOAD(pa0, pa1, pa2, pa3, pb0, pb1, pb2, pb3, 0);
    GLOAD(qa0, qa1, qa2, qa3, qb0, qb1, qb2, qb3, 64);
    SWRITE(0, pa0, pa1, pa2, pa3, pb0, pb1, pb2, pb3);
    if (nK > 2) { GLOAD(pa0, pa1, pa2, pa3, pb0, pb1, pb2, pb3, 128); }
    __syncthreads();   // buf0 ready

    for (int kt = 0; kt < nK; kt += 2) {
        // ---- phase 1: compute tile kt from buf0 ----
        COMPUTE(0);
        SWRITE(1, qa0, qa1, qa2, qa3, qb0, qb1, qb2, qb3);
        if (kt + 3 < nK) { int k0 = (kt + 3) << 6; GLOAD(qa0, qa1, qa2, qa3, qb0, qb1, qb2, qb3, k0); }
        __syncthreads();   // buf1 ready; everyone done with buf0
        // ---- phase 2: compute tile kt+1 from buf1 ----
        COMPUTE(1);
        if (kt + 2 < nK) {
            SWRITE(0, pa0, pa1, pa2, pa3, pb0, pb1, pb2, pb3);
            if (kt + 4 < nK) { int k0 = (kt + 4) << 6; GLOAD(pa0, pa1, pa2, pa3, pb0, pb1, pb2, pb3, k0); }
            __syncthreads();   // buf0 ready; everyone done with buf1
        }
    }
#undef GLOAD
#undef SWRITE
#undef COMPUTE

#pragma unroll
    for (int mi = 0; mi < 4; ++mi) {
#pragma unroll
        for (int ni = 0; ni < 4; ++ni) {
            int gn = bn * 128 + wc * 64 + ni * 16 + l15;
            float bv = bias[gn];
#pragma unroll
            for (int r = 0; r < 4; ++r) {
                int gm = bm * 128 + wr * 64 + mi * 16 + quad * 4 + r;
                float v = acc[mi][ni][r] + bv;
                if (EPI == 0) {
                    if (gn < 384) v *= 0.17677669529663689f;   // hd^-0.5 on q
                    ((ushort_t*)out)[(size_t)gm * N + gn] = f2bf(v);
                } else if (EPI == 1) {
                    v = fast_gelu(v);
                    ((ushort_t*)out)[(size_t)gm * N + gn] = f2bf(v);
                } else if (EPI == 4) {
                    ((ushort_t*)out)[(size_t)gm * N + gn] = f2bf(v);
                } else {
                    size_t dst = (size_t)gm * 384 + gn;
                    ((float*)out)[dst] = resid[dst] + v;
                }
            }
        }
    }
}

// ---------------- window attention v2 (round 7, kept): no barriers ------------
__global__ __launch_bounds__(256) void attn_kernel(
    const ushort_t* __restrict__ qkv,   // [50176,1152] bf16 (q pre-scaled)
    const float* __restrict__ biasT,    // [12][64 j][64 q] f32
    ushort_t* __restrict__ O)           // [50176,384] bf16
{
    __shared__ __align__(16) ushort_t Pl[4][64 * 64];   // 32 KB
    int wave = threadIdx.x >> 6;
    int lane = threadIdx.x & 63;
    int id = blockIdx.x * 4 + wave;     // 0..12287
    int w = id / 12, h = id % 12;
    int quad = lane >> 4, l15 = lane & 15;
    ushort_t* P = Pl[wave];

    short8 aQ[4], bK[4];
#pragma unroll
    for (int t = 0; t < 4; ++t) {
        int row = t * 16 + l15; if (row > 48) row = 48;
        aQ[t] = *(const short8*)(qkv + (size_t)(w * 49 + row) * 1152 + h * 32 + quad * 8);
        bK[t] = *(const short8*)(qkv + (size_t)(w * 49 + row) * 1152 + 384 + h * 32 + quad * 8);
    }
    floatx4 S[4][4];
    floatx4 z4 = (floatx4){0.f, 0.f, 0.f, 0.f};
#pragma unroll
    for (int mt = 0; mt < 4; ++mt)
#pragma unroll
        for (int nt = 0; nt < 4; ++nt)
            S[mt][nt] = __builtin_amdgcn_mfma_f32_16x16x32_bf16(aQ[mt], bK[nt], z4, 0, 0, 0);

    short8 aV[2][2];
#pragma unroll
    for (int mt = 0; mt < 2; ++mt)
#pragma unroll
        for (int kt = 0; kt < 2; ++kt) {
            short8 v;
#pragma unroll
            for (int t = 0; t < 8; ++t) {
                int j = kt * 32 + quad * 8 + t; if (j > 48) j = 48;
                v[t] = (short)qkv[(size_t)(w * 49 + j) * 1152 + 768 + h * 32 + mt * 16 + l15];
            }
            aV[mt][kt] = v;
        }

    const float* bT = biasT + h * 4096;
#pragma unroll
    for (int mt = 0; mt < 4; ++mt) {
        float4 bq[4];
#pragma unroll
        for (int nt = 0; nt < 4; ++nt)
            bq[nt] = *(const float4*)(bT + (nt * 16 + l15) * 64 + mt * 16 + quad * 4);
#pragma unroll
        for (int r = 0; r < 4; ++r) {
            int q = mt * 16 + quad * 4 + r;
            int key = (q ^ (q >> 3)) & 7;
            float mx = -1e30f;
#pragma unroll
            for (int nt = 0; nt < 4; ++nt) {
                int j = nt * 16 + l15;
                float sv = S[mt][nt][r] + ((const float*)&bq[nt])[r];
                if (j >= 49) sv = -1e30f;
                S[mt][nt][r] = sv;
                mx = fmaxf(mx, sv);
            }
#pragma unroll
            for (int off = 1; off < 16; off <<= 1) mx = fmaxf(mx, __shfl_xor(mx, off, 64));
            float sum = 0.f;
#pragma unroll
            for (int nt = 0; nt < 4; ++nt) {
                int j = nt * 16 + l15;
                float p = __expf(S[mt][nt][r] - mx);
                if (j >= 49) p = 0.f;
                S[mt][nt][r] = p;
                sum += p;
            }
#pragma unroll
            for (int off = 1; off < 16; off <<= 1) sum += __shfl_xor(sum, off, 64);
            float inv = 1.f / sum;
#pragma unroll
            for (int nt = 0; nt < 4; ++nt) {
                int j = nt * 16 + l15;
                P[q * 64 + (((j >> 3) ^ key) << 3) + (j & 7)] = f2bf(S[mt][nt][r] * inv);
            }
        }
    }
    asm volatile("s_waitcnt lgkmcnt(0)" ::: "memory");
    __builtin_amdgcn_sched_barrier(0);

    floatx4 Oc[2][4];
#pragma unroll
    for (int mt = 0; mt < 2; ++mt)
#pragma unroll
        for (int nt = 0; nt < 4; ++nt)
            Oc[mt][nt] = z4;
#pragma unroll
    for (int nt = 0; nt < 4; ++nt) {
        int query = nt * 16 + l15;
        int key = (query ^ (query >> 3)) & 7;
#pragma unroll
        for (int kt = 0; kt < 2; ++kt) {
            int slot = ((kt * 4 + quad) ^ key) & 7;
            short8 bP = *(const short8*)&P[query * 64 + slot * 8];
#pragma unroll
            for (int mt = 0; mt < 2; ++mt)
                Oc[mt][nt] = __builtin_amdgcn_mfma_f32_16x16x32_bf16(
                    aV[mt][kt], bP, Oc[mt][nt], 0, 0, 0);
        }
    }
#pragma unroll
    for (int nt = 0; nt < 4; ++nt) {
        int query = nt * 16 + l15;
        if (query < 49) {
#pragma unroll
            for (int mt = 0; mt < 2; ++mt) {
                ushort4 pk;
                pk.x = f2bf(Oc[mt][nt][0]);
                pk.y = f2bf(Oc[mt][nt][1]);
                pk.z = f2bf(Oc[mt][nt][2]);
                pk.w = f2bf(Oc[mt][nt][3]);
                *(ushort4*)(O + (size_t)(w * 49 + query) * 384 + h * 32 + mt * 16 + quad * 4) = pk;
            }
        }
    }
}

// ---------------- launcher ----------------
extern "C" void kernel_launch(void* const* d_in, const int* in_sizes, int n_in,
                              void* d_out, int out_size, void* d_ws, size_t ws_size,
                              hipStream_t stream) {
    const float* x      = (const float*)d_in[0];
    const float* n1g    = (const float*)d_in[1];
    const float* n1b    = (const float*)d_in[2];
    const float* qkv_w  = (const float*)d_in[3];
    const float* qkv_b  = (const float*)d_in[4];
    const float* proj_w = (const float*)d_in[5];
    const float* proj_b = (const float*)d_in[6];
    const float* rpb    = (const float*)d_in[7];
    const float* n2g    = (const float*)d_in[8];
    const float* n2b    = (const float*)d_in[9];
    const float* w1     = (const float*)d_in[10];
    const float* b1     = (const float*)d_in[11];
    const float* w2     = (const float*)d_in[12];
    const float* b2     = (const float*)d_in[13];
    float* out = (float*)d_out;
    char* ws = (char*)d_ws;

    // ws layout (~150.6 MB total):
    ushort_t* qkvbuf = (ushort_t*)ws;                         // 50176*1152*2 (qkv -> Po -> MLP hidden)
    ushort_t* bufA   = (ushort_t*)(ws + 115605504);           // 50176*384*2  (Xw -> O -> H2)
    ushort_t* wq     = (ushort_t*)(ws + 154140672);           // 442368
    ushort_t* wp     = wq + 442368;                           // 147456
    ushort_t* wm1    = wp + 147456;                           // 589824
    ushort_t* wm2    = wm1 + 589824;                          // 589824
    float* biasT     = (float*)(ws + 154140672 + 3538944);    // 12*64*64*4

    cvt_weights<<<2304, 256, 0, stream>>>(qkv_w, proj_w, w1, w2, wq, wp, wm1, wm2);
    build_bias<<<192, 256, 0, stream>>>(rpb, biasT);

    // LN1 + shift + window partition -> Xw (bufA)
    ln_kernel<<<12544, 256, 0, stream>>>(x, n1g, n1b, bufA);
    // QKV projection (q scaled), bf16 out: 392 bm x 9 bn
    gemm_bt<0><<<3528, 256, 0, stream>>>(bufA, wq, qkv_b, qkvbuf, nullptr, 50176, 1152, 384);
    // window attention -> O (bufA, overwrites Xw)
    attn_kernel<<<3072, 256, 0, stream>>>(qkvbuf, biasT, bufA);
    // proj (+bias, bf16, window order) -> Po (qkvbuf reuse): 392 x 3
    gemm_bt<4><<<1176, 256, 0, stream>>>(bufA, wp, proj_b, qkvbuf, nullptr, 50176, 384, 384);
    // fused: x1 = x + window_reverse(Po) -> d_out (f32); LN2(x1) -> H2 (bufA)
    resid_ln<<<12544, 256, 0, stream>>>(x, qkvbuf, n2g, n2b, out, bufA);
    // MLP in two M-halves, hidden reuses qkvbuf (Po already consumed)
    for (int half = 0; half < 2; ++half) {
        size_t mo = (size_t)half * 25088;
        // MLP1: 196 bm x 12 bn
        gemm_bt<1><<<2352, 256, 0, stream>>>(bufA + mo * 384, wm1, b1, qkvbuf, nullptr, 25088, 1536, 384);
        // MLP2: 196 bm x 3 bn
        gemm_bt<3><<<588, 256, 0, stream>>>(qkvbuf, wm2, b2, out + mo * 384, out + mo * 384, 25088, 384, 1536);
    }
}